// Round 11
// baseline (140.278 us; speedup 1.0000x reference)
//
#include <hip/hip_runtime.h>
#include <cfloat>
#include <cstdint>

#define BATCH 16
#define PRIORS 3000
#define NCLS 201
#define NLBL 200           // NCLS - 1
#define TOPN 100
#define SCORE_THR 0.02f
#define NMS_THR 0.45f

// filter v11: 256-thread blocks, 4 waves, 4 consecutive priors per wave.
// float4 loads: a 4-prior group = 804 floats = 201 float4s, 16B-aligned
// (804*p0 % 16 == 0 for p0 % 4 == 0). Per-prior masked max/sum with 4-way
// selects + 4 interleaved shuffle trees. Reduction ORDER differs from
// R2-R10 (probs perturbed ~ulps; bf16-tolerant compare absorbs it).
// Wave-segmented ballot compaction unchanged (exactness machinery intact).
#define FPPB 16                              // priors per block
#define FBLK ((PRIORS + FPPB - 1) / FPPB)    // 188 blocks/image
#define SEGW 64                              // slots per wave-segment
#define SEGS (FBLK * 4)                      // 752 segments/image
#define SLOTS (SEGS * SEGW)                  // 48128 slots/image
#define HOTW 8                               // hot slots per segment
#define OVF_CAP 1024
#define T0 0.08f           // hot threshold: ~315 hot/image (in [105,512] w/ margin)

// nms v11: fast path = gather hot keys, wave-0 register sort of 512,
// MATRIX-resolve scan (independent 64x64 suppression-mask build + bit-dance
// greedy, ~40 cyc/accept vs ~200 of the shuffle chain).
// key = (float_bits(prob)<<32) | (0xFFFFFFFF-oid), oid = p*200+(c-1);
// descending-key order == jnp.argmax order (score desc, first-index ties).
#define NMS_T 1024
#define NBINS 1024         // strata over (key>>48)-SB_BASE (fallback only)
#define HCAP 512
#define SB_BASE 0x3CA3     // floatbits(0.02) >> 16

__device__ __forceinline__ int key_stratum(uint64_t k) {
    int s = (int)(k >> 48) - SB_BASE;
    return s < 0 ? 0 : (s > NBINS - 1 ? NBINS - 1 : s);
}

// ---------------------------------------------------------------------------
// Kernel B (v11): float4 softmax + filter, wave-segmented seg/hot write.
// ---------------------------------------------------------------------------
__global__ __launch_bounds__(256) void score_filter_kernel(
    const float* __restrict__ obj,      // [B][P][NCLS]
    int*         __restrict__ cnt,      // [B] seg-overflow counter (memset 0)
    int*         __restrict__ hcnt,     // [B] hot-overflow counter (memset 0)
    uint64_t*    __restrict__ seg,      // [B][SEGS][SEGW]  all candidates
    uint64_t*    __restrict__ hot,      // [B][SEGS][HOTW]  prob > T0 only
    uint64_t*    __restrict__ ovf,      // [B][OVF_CAP]
    uint64_t*    __restrict__ hovf)     // [B][OVF_CAP]
{
    const int b    = blockIdx.y;
    const int wave = threadIdx.x >> 6;
    const int lane = threadIdx.x & 63;
    const int segId = blockIdx.x * 4 + wave;
    uint64_t* myseg = seg + ((size_t)b * SEGS + segId) * SEGW;
    uint64_t* myhot = hot + ((size_t)b * SEGS + segId) * HOTW;
    const int p0 = blockIdx.x * FPPB + wave * 4;   // multiple of 4

    if (p0 >= PRIORS) {                    // inactive wave: zero its regions
        myseg[lane] = 0ull;
        if (lane < HOTW) myhot[lane] = 0ull;
        return;
    }

    // ---- 4 float4 loads: the whole 4-prior group (alignment proven) ----
    const float4* x4 = (const float4*)(obj + ((size_t)b * PRIORS + p0) * NCLS);
    float4 q[4];
#pragma unroll
    for (int r = 0; r < 4; ++r) {
        int f = r * 64 + lane;
        q[r] = (f < 201) ? x4[f]
                         : make_float4(-FLT_MAX, -FLT_MAX, -FLT_MAX, -FLT_MAX);
    }
    // element e = (r*64+lane)*4 + i; prior pe = e/201 (clamped compare chain;
    // invalid elements carry -FLT_MAX -> exp 0 -> prob 0 -> never pass)

    // ---- per-prior max: masked accumulate + 4 interleaved trees ----
    float mx[4] = { -FLT_MAX, -FLT_MAX, -FLT_MAX, -FLT_MAX };
#pragma unroll
    for (int r = 0; r < 4; ++r) {
        const float* v = (const float*)&q[r];
        int e0 = (r * 64 + lane) * 4;
#pragma unroll
        for (int i = 0; i < 4; ++i) {
            int e = e0 + i;
            int pe = (e >= 603) ? 3 : (e >= 402) ? 2 : (e >= 201) ? 1 : 0;
#pragma unroll
            for (int j = 0; j < 4; ++j)
                if (pe == j) mx[j] = fmaxf(mx[j], v[i]);
        }
    }
    for (int d = 32; d > 0; d >>= 1) {
#pragma unroll
        for (int j = 0; j < 4; ++j)
            mx[j] = fmaxf(mx[j], __shfl_xor(mx[j], d, 64));
    }
    // ---- exp in place ----
#pragma unroll
    for (int r = 0; r < 4; ++r) {
        float* v = (float*)&q[r];
        int e0 = (r * 64 + lane) * 4;
#pragma unroll
        for (int i = 0; i < 4; ++i) {
            int e = e0 + i;
            int pe = (e >= 603) ? 3 : (e >= 402) ? 2 : (e >= 201) ? 1 : 0;
            float m = (pe == 3) ? mx[3] : (pe == 2) ? mx[2]
                     : (pe == 1) ? mx[1] : mx[0];
            v[i] = expf(v[i] - m);
        }
    }
    // ---- per-prior sum: masked accumulate + trees ----
    float se[4] = { 0.0f, 0.0f, 0.0f, 0.0f };
#pragma unroll
    for (int r = 0; r < 4; ++r) {
        const float* v = (const float*)&q[r];
        int e0 = (r * 64 + lane) * 4;
#pragma unroll
        for (int i = 0; i < 4; ++i) {
            int e = e0 + i;
            int pe = (e >= 603) ? 3 : (e >= 402) ? 2 : (e >= 201) ? 1 : 0;
#pragma unroll
            for (int j = 0; j < 4; ++j)
                if (pe == j) se[j] += v[i];
        }
    }
    for (int d = 32; d > 0; d >>= 1) {
#pragma unroll
        for (int j = 0; j < 4; ++j)
            se[j] += __shfl_xor(se[j], d, 64);
    }
    float inv[4] = { 1.0f / se[0], 1.0f / se[1], 1.0f / se[2], 1.0f / se[3] };

    // ---- emit: seg (all passers) + hot (prob > T0), ballot-compacted ----
    int cursor = 0, hcur = 0;
#pragma unroll
    for (int r = 0; r < 4; ++r) {
        const float* v = (const float*)&q[r];
        int e0 = (r * 64 + lane) * 4;
#pragma unroll
        for (int i = 0; i < 4; ++i) {
            int e = e0 + i;
            int pe = (e >= 603) ? 3 : (e >= 402) ? 2 : (e >= 201) ? 1 : 0;
            int ce = e - pe * 201;
            float prob = v[i] * ((pe == 3) ? inv[3] : (pe == 2) ? inv[2]
                               : (pe == 1) ? inv[1] : inv[0]);
            bool pass = (e < 804) && (ce >= 1) && (prob > SCORE_THR);
            uint64_t mask = __ballot(pass);
            bool hotp = pass && (prob > T0);
            uint64_t hmask = __ballot(hotp);
            if (pass) {
                uint32_t oid = (uint32_t)((p0 + pe) * NLBL + (ce - 1));
                uint64_t key = ((uint64_t)__float_as_uint(prob) << 32)
                             | (uint64_t)(0xFFFFFFFFu - oid);
                int idx = cursor + __popcll(mask & ((1ull << lane) - 1ull));
                if (idx < SEGW) {
                    myseg[idx] = key;
                } else {                       // exact seg overflow (never taken)
                    int gi = atomicAdd(&cnt[b], 1);
                    if (gi < OVF_CAP) ovf[(size_t)b * OVF_CAP + gi] = key;
                }
                if (hotp) {
                    int hidx = hcur + __popcll(hmask & ((1ull << lane) - 1ull));
                    if (hidx < HOTW) {
                        myhot[hidx] = key;
                    } else {                   // exact hot overflow (never taken)
                        int gi = atomicAdd(&hcnt[b], 1);
                        if (gi < OVF_CAP) hovf[(size_t)b * OVF_CAP + gi] = key;
                    }
                }
            }
            cursor += (int)__popcll(mask);
            hcur   += (int)__popcll(hmask);
        }
    }
    if (lane >= (cursor < SEGW ? cursor : SEGW)) myseg[lane] = 0ull;
    if (lane < HOTW && lane >= (hcur < HOTW ? hcur : HOTW)) myhot[lane] = 0ull;
}

// ---------------------------------------------------------------------------
// Wave-0 register bitonic sort of 512 u64 keys (8/lane), descending.
// ---------------------------------------------------------------------------
__device__ __forceinline__ void sort512_desc(const uint64_t* skey,
                                             uint64_t K[8], int lane)
{
#pragma unroll
    for (int r = 0; r < 8; ++r) K[r] = skey[r * 64 + lane];
#pragma unroll
    for (int k2 = 2; k2 <= 512; k2 <<= 1) {
#pragma unroll
        for (int j2 = k2 >> 1; j2 >= 64; j2 >>= 1) {     // register stages
            int j2r = j2 >> 6;
#pragma unroll
            for (int r = 0; r < 8; ++r) {
                if ((r & j2r) == 0) {
                    int rp = r | j2r;
                    bool up = ((((r << 6) + lane) & k2) == 0);
                    uint64_t a = K[r], bb = K[rp];
                    uint64_t mxk = a > bb ? a : bb;
                    uint64_t mnk = a > bb ? bb : a;
                    K[r]  = up ? mxk : mnk;
                    K[rp] = up ? mnk : mxk;
                }
            }
        }
#pragma unroll
        for (int j2 = ((k2 >> 1) < 32 ? (k2 >> 1) : 32); j2 >= 1; j2 >>= 1) {
#pragma unroll
            for (int r = 0; r < 8; ++r) {                // shuffle stages
                uint64_t o = __shfl_xor((unsigned long long)K[r], j2, 64);
                bool up = ((((r << 6) + lane) & k2) == 0);
                bool lower = ((lane & j2) == 0);
                K[r] = (up == lower) ? (K[r] > o ? K[r] : o)
                                     : (K[r] < o ? K[r] : o);
            }
        }
    }
}

// ---------------------------------------------------------------------------
// Wave-0 MATRIX scan over sorted K[8] (desc). Per 64-batch:
//   phase A: parallel IoU vs accepted list (LDS);
//   build:   64 independent iterations -> per-lane 64-bit mask M
//            (bit jj = candidate jj suppresses me; self-bit included);
//   resolve: bit-dance greedy, ~40 cyc/accept. Self-bit removes the
//            accepted lane (matches .at[i].set(-1)). Invalid/dead lanes
//            are never accepted, so their M columns are never applied.
// Box/area/IoU expressions bit-identical to the reference's bo/areas.
// ---------------------------------------------------------------------------
__device__ __forceinline__ int scan_matrix_w0(
    const uint64_t K[8], int b, const float4* __restrict__ dbox, float ofb,
    float4* abox, float* aarea, int na, float* __restrict__ out, int lane)
{
#pragma unroll
    for (int r = 0; r < 8; ++r) {
        if (na >= TOPN) break;
        uint64_t myk = K[r];
        bool valid = (myk != 0ull);
        uint32_t oid = 0xFFFFFFFFu - (uint32_t)myk;
        int p = valid ? (int)(oid / NLBL) : 0;
        int c = valid ? ((int)(oid - (uint32_t)p * NLBL) + 1) : 1;
        float4 db = dbox[p];
        float lof = (float)c * ofb;
        float qx1 = db.x + lof, qy1 = db.y + lof;
        float qx2 = db.z + lof, qy2 = db.w + lof;
        float aq = (qx2 - qx1) * (qy2 - qy1);
        // ---- phase A: vs accepts from earlier batches ----
        bool dead = false;
        for (int l = 0; l < na; ++l) {
            float4 a = abox[l];
            float ix1 = fmaxf(qx1, a.x), iy1 = fmaxf(qy1, a.y);
            float ix2 = fminf(qx2, a.z), iy2 = fminf(qy2, a.w);
            float inter = fmaxf(ix2 - ix1, 0.0f) * fmaxf(iy2 - iy1, 0.0f);
            float iou = inter / (aq + aarea[l] - inter);  // NaN>thr==false
            if (iou > NMS_THR) dead = true;
        }
        bool aliveB = valid && !dead;
        uint64_t alive = __ballot(aliveB);
        if (alive == 0ull) continue;
        // ---- build suppression mask (independent iterations, pipelined) ----
        uint64_t M = 0ull;
#pragma unroll 4
        for (int jj = 0; jj < 64; ++jj) {
            float ax1 = __shfl(qx1, jj, 64);
            float ay1 = __shfl(qy1, jj, 64);
            float ax2 = __shfl(qx2, jj, 64);
            float ay2 = __shfl(qy2, jj, 64);
            float aa  = __shfl(aq,  jj, 64);
            float ix1 = fmaxf(qx1, ax1), iy1 = fmaxf(qy1, ay1);
            float ix2 = fminf(qx2, ax2), iy2 = fminf(qy2, ay2);
            float inter = fmaxf(ix2 - ix1, 0.0f) * fmaxf(iy2 - iy1, 0.0f);
            float iou = inter / (aq + aa - inter);
            if (iou > NMS_THR) M |= (1ull << jj);
        }
        // ---- greedy resolve (bit-dance) ----
        while (alive != 0ull && na < TOPN) {
            int j = __ffsll((unsigned long long)alive) - 1;
            if (lane == j) {                   // accepted lane writes
                abox[na]  = make_float4(qx1, qy1, qx2, qy2);
                aarea[na] = aq;
                float* o = out + ((size_t)b * TOPN + na) * 6;
                o[0] = fminf(fmaxf(db.x, 0.0f), 1.0f);
                o[1] = fminf(fmaxf(db.y, 0.0f), 1.0f);
                o[2] = fminf(fmaxf(db.z, 0.0f), 1.0f);
                o[3] = fminf(fmaxf(db.w, 0.0f), 1.0f);
                o[4] = __uint_as_float((uint32_t)(myk >> 32));
                o[5] = (float)c;
            }
            na++;
            aliveB = aliveB && !((M >> j) & 1ull);   // self-bit kills lane j
            alive = __ballot(aliveB);
        }
    }
    return na;
}

// ---------------------------------------------------------------------------
// Fallback helpers (exact; never taken with this data).
// ---------------------------------------------------------------------------
__device__ __forceinline__ int scan_sorted_w0(
    const uint64_t K[8], int b, const float4* __restrict__ dbox, float ofb,
    float4* abox, float* aarea, int na, float* __restrict__ out, int lane)
{
    return scan_matrix_w0(K, b, dbox, ofb, abox, aarea, na, out, lane);
}

__device__ __forceinline__ int scan_step_w0(
    uint64_t key, int b, const float4* __restrict__ dbox, float ofb,
    float4* abox, float* aarea, int na, float* __restrict__ out, int lane)
{
    uint32_t oid = 0xFFFFFFFFu - (uint32_t)key;
    int p = (int)(oid / NLBL);
    int c = (int)(oid - (uint32_t)p * NLBL) + 1;
    float4 db = dbox[p];
    float lo = (float)c * ofb;
    float qx1 = db.x + lo, qy1 = db.y + lo;
    float qx2 = db.z + lo, qy2 = db.w + lo;
    float aq = (qx2 - qx1) * (qy2 - qy1);
    bool sup = false;
    for (int l = lane; l < na; l += 64) {
        float4 a = abox[l];
        float ix1 = fmaxf(qx1, a.x), iy1 = fmaxf(qy1, a.y);
        float ix2 = fminf(qx2, a.z), iy2 = fminf(qy2, a.w);
        float inter = fmaxf(ix2 - ix1, 0.0f) * fmaxf(iy2 - iy1, 0.0f);
        float iou = inter / (aq + aarea[l] - inter);
        if (iou > NMS_THR) sup = true;
    }
    if (__ballot(sup) == 0ull) {
        if (lane == 0) {
            abox[na]  = make_float4(qx1, qy1, qx2, qy2);
            aarea[na] = aq;
            float* o = out + ((size_t)b * TOPN + na) * 6;
            o[0] = fminf(fmaxf(db.x, 0.0f), 1.0f);
            o[1] = fminf(fmaxf(db.y, 0.0f), 1.0f);
            o[2] = fminf(fmaxf(db.z, 0.0f), 1.0f);
            o[3] = fminf(fmaxf(db.w, 0.0f), 1.0f);
            o[4] = __uint_as_float((uint32_t)(key >> 32));
            o[5] = (float)c;
        }
        __threadfence_block();
        return na + 1;
    }
    return na;
}

// ---------------------------------------------------------------------------
// Kernel C (v11): one block per image.
// FAST PATH: gather hot keys -> wave 0 register-sorts 512 while waves 1-15
// decode -> matrix scan. EXACT FALLBACK (hot>512 or accepts<100): hist +
// chunk loop + overfull-stratum argmax, recomputed from na=0.
// ---------------------------------------------------------------------------
__global__ __launch_bounds__(NMS_T) void nms_kernel(
    const float*    __restrict__ deltas,  // [B][P][4]
    const float*    __restrict__ priors,  // [P][4]
    const int*      __restrict__ cnt,     // [B] seg-overflow counts
    const int*      __restrict__ hcnt,    // [B] hot-overflow counts
    const uint64_t* __restrict__ seg,     // [B][SLOTS]
    const uint64_t* __restrict__ hot,     // [B][SEGS*HOTW]
    const uint64_t* __restrict__ ovf,     // [B][OVF_CAP]
    const uint64_t* __restrict__ hovf,    // [B][OVF_CAP]
    float*          __restrict__ out)     // [B][TOPN][6]
{
    __shared__ float4   dbox[PRIORS];     // 48 KB decoded boxes
    __shared__ int      sufx[NBINS];      // fallback suffix counts
    __shared__ uint64_t skey[HCAP];       // collected keys (<=512)
    __shared__ float4   abox[112];        // accepted offset boxes (<=100)
    __shared__ float    aarea[112];
    __shared__ uint64_t rk[NMS_T / 64];
    __shared__ float    wredF[NMS_T / 64];
    __shared__ int      wtotS[NMS_T / 64];
    __shared__ int      carryS[NMS_T / 64];
    __shared__ int cntC, loS, naS;
    __shared__ uint64_t fkS;

    const int b    = blockIdx.x;
    const int tid  = threadIdx.x;
    const int wave = tid >> 6;
    const int lane = tid & 63;
    const uint64_t* slots  = seg  + (size_t)b * SLOTS;
    const uint64_t* hslots = hot  + (size_t)b * SEGS * HOTW;
    int n_ovf  = cnt[b];  if (n_ovf  > OVF_CAP) n_ovf  = OVF_CAP;
    int n_hovf = hcnt[b]; if (n_hovf > OVF_CAP) n_hovf = OVF_CAP;
    const uint64_t* ovfp  = ovf  + (size_t)b * OVF_CAP;
    const uint64_t* hovfp = hovf + (size_t)b * OVF_CAP;

    if (tid == 0) { cntC = 0; naS = 0; }
    if (lane == 0) wredF[wave] = -FLT_MAX;
    if (tid < HCAP) skey[tid] = 0ull;      // pre-zero (pad for the sort)
    __syncthreads();

    // ======== FAST PATH: collect hot keys (strict desc prefix) ========
    for (int j = tid; j < SEGS * HOTW; j += NMS_T) {
        uint64_t k = hslots[j];
        if (k) { int i = atomicAdd(&cntC, 1); if (i < HCAP) skey[i] = k; }
    }
    for (int j = tid; j < n_hovf; j += NMS_T) {
        uint64_t k = hovfp[j];
        if (k) { int i = atomicAdd(&cntC, 1); if (i < HCAP) skey[i] = k; }
    }
    __syncthreads();
    int hc = cntC;                          // uniform
    bool decoded = false;
    if (hc <= HCAP) {
        if (wave == 0) {
            uint64_t K[8];
            sort512_desc(skey, K, lane);
            __syncthreads();                // join: decode done on waves 1-15
            float ofb;
            {
                float v = (lane < NMS_T / 64) ? wredF[lane] : -FLT_MAX;
                for (int d = 32; d > 0; d >>= 1) v = fmaxf(v, __shfl_xor(v, d, 64));
                ofb = v + 1.0f;
            }
            int na = scan_matrix_w0(K, b, dbox, ofb, abox, aarea, 0, out, lane);
            if (lane == 0) naS = na;
        } else {
            // waves 1-15: decode 3000 priors -> LDS dbox (200 each)
            int base0 = (wave - 1) * 200;
            float lmax = -FLT_MAX;
            for (int p = base0 + lane; p < base0 + 200; p += 64) {
                float4 d4 = ((const float4*)deltas)[(size_t)b * PRIORS + p];
                float4 pr = ((const float4*)priors)[p];
                float cx = d4.x * 0.1f * pr.z + pr.x;
                float cy = d4.y * 0.1f * pr.w + pr.y;
                float w  = expf(d4.z * 0.2f) * pr.z;
                float h  = expf(d4.w * 0.2f) * pr.w;
                float x1 = cx - 0.5f * w, y1 = cy - 0.5f * h;
                float x2 = cx + 0.5f * w, y2 = cy + 0.5f * h;
                dbox[p] = make_float4(x1, y1, x2, y2);
                lmax = fmaxf(lmax, fmaxf(fmaxf(x1, y1), fmaxf(x2, y2)));
            }
            for (int d = 32; d > 0; d >>= 1)
                lmax = fmaxf(lmax, __shfl_xor(lmax, d, 64));
            if (lane == 0) wredF[wave] = lmax;
            __syncthreads();                // pairs with wave 0's post-sort barrier
        }
        decoded = true;
        __syncthreads();
    }

    // ======== EXACT FALLBACK (never with this data) ========
    if (naS < TOPN) {
        if (!decoded) {
            float lmax = -FLT_MAX;
            for (int p = tid; p < PRIORS; p += NMS_T) {
                float4 d4 = ((const float4*)deltas)[(size_t)b * PRIORS + p];
                float4 pr = ((const float4*)priors)[p];
                float cx = d4.x * 0.1f * pr.z + pr.x;
                float cy = d4.y * 0.1f * pr.w + pr.y;
                float w  = expf(d4.z * 0.2f) * pr.z;
                float h  = expf(d4.w * 0.2f) * pr.w;
                float x1 = cx - 0.5f * w, y1 = cy - 0.5f * h;
                float x2 = cx + 0.5f * w, y2 = cy + 0.5f * h;
                dbox[p] = make_float4(x1, y1, x2, y2);
                lmax = fmaxf(lmax, fmaxf(fmaxf(x1, y1), fmaxf(x2, y2)));
            }
            for (int d = 32; d > 0; d >>= 1)
                lmax = fmaxf(lmax, __shfl_xor(lmax, d, 64));
            if (lane == 0) wredF[wave] = lmax;
        }
        sufx[tid] = 0;
        if (tid == 0) naS = 0;              // restart: rows rewritten identically
        __syncthreads();
        for (int j = tid; j < SLOTS; j += NMS_T) {
            uint64_t k = slots[j];
            if (k) atomicAdd(&sufx[key_stratum(k)], 1);
        }
        for (int j = tid; j < n_ovf; j += NMS_T) {
            uint64_t k = ovfp[j];
            if (k) atomicAdd(&sufx[key_stratum(k)], 1);
        }
        __syncthreads();
        {
            int v = sufx[64 * wave + lane];
            int s = v;
            for (int d = 1; d < 64; d <<= 1) {
                int t = __shfl_down(s, d, 64);
                if (lane + d < 64) s += t;
            }
            if (lane == 0) wtotS[wave] = s;
            __syncthreads();
            if (wave == 0 && lane < NMS_T / 64) {
                int tv = wtotS[lane];
                int ts = tv;
                for (int d = 1; d < NMS_T / 64; d <<= 1) {
                    int t = __shfl_down(ts, d, 64);
                    if (lane + d < NMS_T / 64) ts += t;
                }
                carryS[lane] = ts - tv;
            }
            __syncthreads();
            sufx[64 * wave + lane] = s + carryS[wave];
        }
        int curHi = NBINS;
        for (;;) {
            __syncthreads();
            int naCur = naS;
            int A = (curHi < NBINS) ? sufx[curHi] : 0;
            int remaining = sufx[0] - A;
            if (naCur >= TOPN || remaining <= 0 || curHi <= 0) break;
            int target = A + HCAP;
            if (tid == 0) { loS = curHi; cntC = 0; }
            __syncthreads();
            if (tid < curHi) {
                if (sufx[tid] <= target && (tid == 0 || sufx[tid - 1] > target))
                    loS = tid;
            }
            __syncthreads();
            int lo = loS;

            if (lo < curHi) {
                for (int j = tid; j < SLOTS; j += NMS_T) {
                    uint64_t k = slots[j];
                    if (k) {
                        int s = key_stratum(k);
                        if (s >= lo && s < curHi) {
                            int i = atomicAdd(&cntC, 1);
                            if (i < HCAP) skey[i] = k;
                        }
                    }
                }
                for (int j = tid; j < n_ovf; j += NMS_T) {
                    uint64_t k = ovfp[j];
                    if (k) {
                        int s = key_stratum(k);
                        if (s >= lo && s < curHi) {
                            int i = atomicAdd(&cntC, 1);
                            if (i < HCAP) skey[i] = k;
                        }
                    }
                }
                __syncthreads();
                if (tid < HCAP && tid >= cntC) skey[tid] = 0ull;
                __syncthreads();
                if (wave == 0) {
                    uint64_t K[8];
                    sort512_desc(skey, K, lane);
                    float ofb;
                    {
                        float v = (lane < NMS_T / 64) ? wredF[lane] : -FLT_MAX;
                        for (int d = 32; d > 0; d >>= 1) v = fmaxf(v, __shfl_xor(v, d, 64));
                        ofb = v + 1.0f;
                    }
                    int na = scan_sorted_w0(K, b, dbox, ofb, abox, aarea, naS, out, lane);
                    if (lane == 0) naS = na;
                }
                curHi = lo;
            } else {
                float ofbT;
                {
                    float v = (lane < NMS_T / 64) ? wredF[lane] : -FLT_MAX;
                    for (int d = 32; d > 0; d >>= 1) v = fmaxf(v, __shfl_xor(v, d, 64));
                    ofbT = v + 1.0f;
                }
                int s = curHi - 1;
                uint64_t lastK = ~0ull;
                for (;;) {
                    __syncthreads();
                    if (naS >= TOPN) break;
                    uint64_t bk = 0ull;
                    for (int j = tid; j < SLOTS; j += NMS_T) {
                        uint64_t k = slots[j];
                        if (k && key_stratum(k) == s && k < lastK && k > bk) bk = k;
                    }
                    for (int j = tid; j < n_ovf; j += NMS_T) {
                        uint64_t k = ovfp[j];
                        if (k && key_stratum(k) == s && k < lastK && k > bk) bk = k;
                    }
                    for (int d = 32; d > 0; d >>= 1) {
                        uint64_t o = __shfl_xor((unsigned long long)bk, d, 64);
                        bk = (o > bk) ? o : bk;
                    }
                    if (lane == 0) rk[wave] = bk;
                    __syncthreads();
                    if (tid == 0) {
                        uint64_t fk = rk[0];
                        for (int w = 1; w < NMS_T / 64; ++w) fk = (rk[w] > fk) ? rk[w] : fk;
                        fkS = fk;
                    }
                    __syncthreads();
                    uint64_t fk = fkS;
                    if (fk == 0ull) break;
                    if (wave == 0) {
                        int nal = naS;
                        nal = scan_step_w0(fk, b, dbox, ofbT, abox, aarea, nal, out, lane);
                        if (lane == 0) naS = nal;
                    }
                    lastK = fk;
                }
                curHi = s;
            }
        }
    }
    // ---- zero-fill rows naS..99 (harness poisons d_out) ----
    __syncthreads();
    int naF = naS;
    for (int idx = tid; idx < (TOPN - naF) * 6; idx += NMS_T)
        out[(size_t)b * TOPN * 6 + (size_t)naF * 6 + idx] = 0.0f;
}

// ---------------------------------------------------------------------------
extern "C" void kernel_launch(void* const* d_in, const int* in_sizes, int n_in,
                              void* d_out, int out_size, void* d_ws, size_t ws_size,
                              hipStream_t stream)
{
    const float* deltas = (const float*)d_in[0];
    const float* obj    = (const float*)d_in[1];
    const float* priors = (const float*)d_in[2];
    float* out = (float*)d_out;

    char* ws = (char*)d_ws;
    int*      cnt  = (int*)ws;                              // 64 B
    int*      hcnt = (int*)(ws + 64);                       // 64 B
    uint64_t* hotA = (uint64_t*)(ws + 256);                 // B*SEGS*HOTW*8 = 770 KB
    uint64_t* segA = hotA + (size_t)BATCH * SEGS * HOTW;    // B*SLOTS*8 = 6.2 MB
    uint64_t* ovfA = segA + (size_t)BATCH * SLOTS;          // 128 KB
    uint64_t* hovA = ovfA + (size_t)BATCH * OVF_CAP;        // 128 KB

    hipMemsetAsync(ws, 0, 128, stream);
    dim3 fg(FBLK, BATCH, 1);
    score_filter_kernel<<<fg, 256, 0, stream>>>(obj, cnt, hcnt, segA, hotA, ovfA, hovA);
    nms_kernel<<<BATCH, NMS_T, 0, stream>>>(deltas, priors, cnt, hcnt,
                                            segA, hotA, ovfA, hovA, out);
}